// Round 2
// baseline (311.758 us; speedup 1.0000x reference)
//
#include <hip/hip_runtime.h>
#include <hip/hip_bf16.h>
#include <math.h>

#define NH 8
#define HS 64
#define VOCAB 16384
#define QPH 2048                         // queries per head = b(4) * t(512)
#define SCALE 0.04419417382415922f       // 1/sqrt(512)

typedef __attribute__((ext_vector_type(8))) short bf16x8;
typedef __attribute__((ext_vector_type(4))) float f32x4;

static __device__ __forceinline__ unsigned short f2bf(float f) {
    __hip_bfloat16 h = __float2bfloat16(f);
    unsigned short u;
    __builtin_memcpy(&u, &h, 2);
    return u;
}

// ---------------- Kernel 1: Q prep = encoder + sinusoidal PE + LayerNorm -> bf16 ----
// one wave per (head, q) row of 64 elements; 4 rows per 256-thread block
__global__ void qprep(const float* __restrict__ x, const float* __restrict__ enc_w,
                      const float* __restrict__ enc_b, const float* __restrict__ ln_w,
                      const float* __restrict__ ln_b, unsigned short* __restrict__ qbf) {
    int row  = blockIdx.x * 4 + (threadIdx.x >> 6);   // 0..16383 = n*2048 + q
    int lane = threadIdx.x & 63;                      // = h
    int n = row >> 11;
    int q = row & 2047;
    int t = q & 511;
    int h = lane;
    float xv = x[q];                                  // x flat is (b*512 + t) == q
    int d = n * 64 + h;
    // sinusoidal PE: div_i = exp(2i * (-ln(10000)/64)), even h -> sin, odd -> cos
    float h2  = (float)(h & ~1);
    float div = __expf(h2 * (-9.210340371976184f / 64.0f));
    float ang = (float)t * div;
    float pe  = (h & 1) ? cosf(ang) : sinf(ang);
    float v = xv * enc_w[d] + enc_b[d] + pe;
    // LayerNorm over the 64 lanes
    float s = v;
    #pragma unroll
    for (int off = 1; off < 64; off <<= 1) s += __shfl_xor(s, off);
    float mu = s * (1.0f / 64.0f);
    float dd = v - mu;
    float s2 = dd * dd;
    #pragma unroll
    for (int off = 1; off < 64; off <<= 1) s2 += __shfl_xor(s2, off);
    float var = s2 * (1.0f / 64.0f);
    float y = dd * rsqrtf(var + 1e-5f) * ln_w[h] + ln_b[h];
    qbf[row * 64 + h] = f2bf(y);
}

// ---------------- Kernel 2: E -> bf16 cast + g[n][v] = E[n][v,:] . dec_w[n*64:] ------
// each thread handles one float4 (4 elems); 16 threads cover one v-row
__global__ void eprep(const float* __restrict__ emb, const float* __restrict__ dec_w,
                      unsigned short* __restrict__ ebf, float* __restrict__ g) {
    int i4  = blockIdx.x * 256 + threadIdx.x;   // float4 index, total 2097152
    int row = i4 >> 4;                          // (n, v) row
    int c   = i4 & 15;
    int n   = row >> 14;
    f32x4 v = ((const f32x4*)emb)[i4];
    ushort4 u = make_ushort4(f2bf(v.x), f2bf(v.y), f2bf(v.z), f2bf(v.w));
    ((ushort4*)ebf)[i4] = u;
    const float* dw = dec_w + n * 64 + c * 4;
    float p = v.x * dw[0] + v.y * dw[1] + v.z * dw[2] + v.w * dw[3];
    p += __shfl_xor(p, 1); p += __shfl_xor(p, 2);
    p += __shfl_xor(p, 4); p += __shfl_xor(p, 8);
    if (c == 0) g[row] = p;
}

// ---------------- Kernel 3: main — S^T = E_tile @ Q^T (MFMA), fused exp/g epilogue ----
// grid 256: head = blockIdx&7 (head-per-XCD), qblk = blockIdx>>3 (64 q per block)
// block 512 = 8 waves: qsub = wave&3 (16 q each), vhalf = wave>>2 (8192 v each)
__global__ void __launch_bounds__(512)
attn(const unsigned short* __restrict__ qbf, const unsigned short* __restrict__ ebf,
     const float* __restrict__ g, float2* __restrict__ numden) {
    __shared__ __align__(16) short Ebuf[2][32 * 72];   // padded stride 72 shorts
    __shared__ __align__(16) float Gbuf[2][32];
    __shared__ __align__(16) float Red[2][2][64];      // [vhalf][num|den][q]

    int head = blockIdx.x & 7;
    int qblk = blockIdx.x >> 3;
    int tid  = threadIdx.x;
    int wave = tid >> 6;
    int lane = tid & 63;
    int quad = lane >> 4;
    int l15  = lane & 15;
    int vhalf = wave >> 2;
    int qsub  = wave & 3;
    int qbase = qblk * 64 + qsub * 16;

    // persistent Q B-frags: B[k=hs][n=q], lane: n=l15, k = kc*32 + quad*8 + j
    const short* qrow = (const short*)qbf + (size_t)(head * QPH + qbase + l15) * HS;
    bf16x8 qf0 = *(const bf16x8*)(qrow + quad * 8);
    bf16x8 qf1 = *(const bf16x8*)(qrow + 32 + quad * 8);

    const short* ehead = (const short*)ebf + (size_t)head * VOCAB * HS;
    const float* ghead = g + head * VOCAB;

    float numacc = 0.f, denacc = 0.f;

    // staging role: first 256 threads stage vhalf0 buffer, rest vhalf1
    int sbuf = tid >> 8;
    int sc   = tid & 255;
    int srow = sc >> 3, sseg = sc & 7;   // 32 rows x 8 chunks of 16B

    for (int it = 0; it < 256; ++it) {
        __syncthreads();
        int vbs = sbuf * 8192 + it * 32;
        f32x4 ev = *(const f32x4*)(ehead + (size_t)(vbs + srow) * HS + sseg * 8);
        *(f32x4*)&Ebuf[sbuf][srow * 72 + sseg * 8] = ev;
        if (sc < 32) Gbuf[sbuf][sc] = ghead[sbuf * 8192 + it * 32 + sc];
        __syncthreads();

        const short* eb = &Ebuf[vhalf][0];
        // A-frags: A[m=v][k=hs], lane: m=l15 (+16*mt), k = kc*32 + quad*8 + j
        bf16x8 a00 = *(const bf16x8*)(eb + (l15)      * 72 + quad * 8);
        bf16x8 a01 = *(const bf16x8*)(eb + (l15)      * 72 + 32 + quad * 8);
        bf16x8 a10 = *(const bf16x8*)(eb + (16 + l15) * 72 + quad * 8);
        bf16x8 a11 = *(const bf16x8*)(eb + (16 + l15) * 72 + 32 + quad * 8);
        f32x4 acc0 = {0.f, 0.f, 0.f, 0.f};
        f32x4 acc1 = {0.f, 0.f, 0.f, 0.f};
        acc0 = __builtin_amdgcn_mfma_f32_16x16x32_bf16(a00, qf0, acc0, 0, 0, 0);
        acc0 = __builtin_amdgcn_mfma_f32_16x16x32_bf16(a01, qf1, acc0, 0, 0, 0);
        acc1 = __builtin_amdgcn_mfma_f32_16x16x32_bf16(a10, qf0, acc1, 0, 0, 0);
        acc1 = __builtin_amdgcn_mfma_f32_16x16x32_bf16(a11, qf1, acc1, 0, 0, 0);

        // D layout: col = l15 = q, row = quad*4 + reg = v-within-tile
        f32x4 gv0 = *(const f32x4*)&Gbuf[vhalf][quad * 4];
        f32x4 gv1 = *(const f32x4*)&Gbuf[vhalf][16 + quad * 4];
        #pragma unroll
        for (int r = 0; r < 4; ++r) {
            float p0 = __expf(acc0[r] * SCALE);
            float p1 = __expf(acc1[r] * SCALE);
            denacc += p0 + p1;
            numacc += p0 * gv0[r] + p1 * gv1[r];
        }
    }

    // reduce partials across the 4 quads holding the same q
    numacc += __shfl_xor(numacc, 16); numacc += __shfl_xor(numacc, 32);
    denacc += __shfl_xor(denacc, 16); denacc += __shfl_xor(denacc, 32);
    __syncthreads();
    if (lane < 16) {
        Red[vhalf][0][qsub * 16 + lane] = numacc;
        Red[vhalf][1][qsub * 16 + lane] = denacc;
    }
    __syncthreads();
    if (tid < 64) {
        float num = Red[0][0][tid] + Red[1][0][tid];
        float den = Red[0][1][tid] + Red[1][1][tid];
        numden[head * QPH + qblk * 64 + tid] = make_float2(num, den);
    }
}

// ---------------- Kernel 4: out[q] = dec_b + sum_n num/den ---------------------------
__global__ void fin(const float2* __restrict__ numden, const float* __restrict__ dec_b,
                    float* __restrict__ out) {
    int q = blockIdx.x * 256 + threadIdx.x;   // 0..2047
    float s = dec_b[0];
    #pragma unroll
    for (int n = 0; n < NH; ++n) {
        float2 nd = numden[n * QPH + q];
        s += nd.x / nd.y;
    }
    out[q] = s;
}

extern "C" void kernel_launch(void* const* d_in, const int* in_sizes, int n_in,
                              void* d_out, int out_size, void* d_ws, size_t ws_size,
                              hipStream_t stream) {
    const float* x     = (const float*)d_in[0];
    const float* emb   = (const float*)d_in[1];
    const float* enc_w = (const float*)d_in[2];
    const float* enc_b = (const float*)d_in[3];
    const float* ln_w  = (const float*)d_in[4];
    const float* ln_b  = (const float*)d_in[5];
    const float* dec_w = (const float*)d_in[6];
    const float* dec_b = (const float*)d_in[7];
    float* out = (float*)d_out;

    char* ws = (char*)d_ws;
    unsigned short* qbf = (unsigned short*)(ws);                       // 2 MB
    unsigned short* ebf = (unsigned short*)(ws + 2097152);             // 16.75 MB
    float*          g   = (float*)(ws + 2097152 + 16777216);           // 512 KB
    float2*      numden = (float2*)(ws + 2097152 + 16777216 + 524288); // 128 KB

    hipLaunchKernelGGL(qprep, dim3(4096), dim3(256), 0, stream, x, enc_w, enc_b, ln_w, ln_b, qbf);
    hipLaunchKernelGGL(eprep, dim3(8192), dim3(256), 0, stream, emb, dec_w, ebf, g);
    hipLaunchKernelGGL(attn,  dim3(256),  dim3(512), 0, stream, qbf, ebf, g, numden);
    hipLaunchKernelGGL(fin,   dim3(8),    dim3(256), 0, stream, numden, dec_b, out);
}

// Round 3
// 170.216 us; speedup vs baseline: 1.8315x; 1.8315x over previous
//
#include <hip/hip_runtime.h>
#include <hip/hip_bf16.h>
#include <math.h>

#define NH 8
#define HS 64
#define VOCAB 16384
#define QPH 2048                         // queries per head = b(4) * t(512)
// fold 1/sqrt(512) * log2(e) into Q so the epilogue is p = exp2(score)
#define QSCALE (0.04419417382415922f * 1.4426950408889634f)

typedef __attribute__((ext_vector_type(8))) short bf16x8;
typedef __attribute__((ext_vector_type(4))) float f32x4;

static __device__ __forceinline__ unsigned short f2bf(float f) {
    __hip_bfloat16 h = __float2bfloat16(f);
    unsigned short u;
    __builtin_memcpy(&u, &h, 2);
    return u;
}

static __device__ __forceinline__ float fexp2(float x) {
#if __has_builtin(__builtin_amdgcn_exp2f)
    return __builtin_amdgcn_exp2f(x);     // v_exp_f32 directly
#else
    return __expf(x * 0.6931471805599453f);
#endif
}

// ---------------- Kernel 1: fused prep -----------------------------------------------
// blocks [0,8192):   E -> bf16 cast + g[n][v] = E[n][v,:] . dec_w[n*64:]
// blocks [8192,12288): Q = LayerNorm(enc(x) + PE) * QSCALE -> bf16, wave per row
__global__ void prep(const float* __restrict__ x, const float* __restrict__ emb,
                     const float* __restrict__ enc_w, const float* __restrict__ enc_b,
                     const float* __restrict__ ln_w, const float* __restrict__ ln_b,
                     const float* __restrict__ dec_w,
                     unsigned short* __restrict__ qbf, unsigned short* __restrict__ ebf,
                     float* __restrict__ g) {
    if (blockIdx.x < 8192) {
        int i4  = blockIdx.x * 256 + threadIdx.x;   // float4 index, total 2097152
        int row = i4 >> 4;                          // (n, v) row
        int c   = i4 & 15;
        int n   = row >> 14;
        f32x4 v = ((const f32x4*)emb)[i4];
        ushort4 u = make_ushort4(f2bf(v.x), f2bf(v.y), f2bf(v.z), f2bf(v.w));
        ((ushort4*)ebf)[i4] = u;
        const float* dw = dec_w + n * 64 + c * 4;
        float p = v.x * dw[0] + v.y * dw[1] + v.z * dw[2] + v.w * dw[3];
        p += __shfl_xor(p, 1); p += __shfl_xor(p, 2);
        p += __shfl_xor(p, 4); p += __shfl_xor(p, 8);
        if (c == 0) g[row] = p;
    } else {
        int row  = (blockIdx.x - 8192) * 4 + (threadIdx.x >> 6);  // n*2048 + q
        int h    = threadIdx.x & 63;
        int n = row >> 11;
        int q = row & 2047;
        int t = q & 511;
        float xv = x[q];
        int d = n * 64 + h;
        float h2  = (float)(h & ~1);
        float div = __expf(h2 * (-9.210340371976184f / 64.0f));
        float ang = (float)t * div;
        float pe  = (h & 1) ? __cosf(ang) : __sinf(ang);
        float v = xv * enc_w[d] + enc_b[d] + pe;
        float s = v;
        #pragma unroll
        for (int off = 1; off < 64; off <<= 1) s += __shfl_xor(s, off);
        float mu = s * (1.0f / 64.0f);
        float dd = v - mu;
        float s2 = dd * dd;
        #pragma unroll
        for (int off = 1; off < 64; off <<= 1) s2 += __shfl_xor(s2, off);
        float var = s2 * (1.0f / 64.0f);
        float y = dd * rsqrtf(var + 1e-5f) * ln_w[h] + ln_b[h];
        qbf[row * 64 + h] = f2bf(y * QSCALE);
    }
}

// ---------------- Kernel 2: attn — barrier-free, LDS-free ---------------------------
// grid 1024, block 256 (4 waves). blockIdx = qchunk(8) * 128 + (vslice(16)*8 + head(8))
// => blockIdx % 8 == head: each XCD's round-robin share touches ONE head's E (2MB < 4MB L2).
// Wave w handles q64-chunk wq = qchunk*4+w (64 q, Q persistent in VGPRs) over a
// 1024-row vocab slice. Partial num/den merged via global float atomics.
__global__ void __launch_bounds__(256, 4)
attn(const unsigned short* __restrict__ qbf, const unsigned short* __restrict__ ebf,
     const float* __restrict__ g, float* __restrict__ part) {
    int tid  = threadIdx.x;
    int w    = tid >> 6;
    int lane = tid & 63;
    int quad = lane >> 4;
    int l15  = lane & 15;
    int hv     = blockIdx.x & 127;
    int head   = hv & 7;
    int vslice = hv >> 3;
    int qchunk = blockIdx.x >> 7;
    int qbase  = (qchunk * 4 + w) * 64;

    // persistent Q B-frags: B[k=hs][n=q], lane: n=l15, k = kf*32 + quad*8 + j
    const short* qp = (const short*)qbf + (size_t)(head * QPH + qbase) * HS;
    bf16x8 qf[4][2];
    #pragma unroll
    for (int qt = 0; qt < 4; ++qt) {
        const short* qrow = qp + (qt * 16 + l15) * HS + quad * 8;
        qf[qt][0] = *(const bf16x8*)(qrow);
        qf[qt][1] = *(const bf16x8*)(qrow + 32);
    }

    const short* ep = (const short*)ebf + ((size_t)head * VOCAB + vslice * 1024) * HS;
    const float* gp = g + head * VOCAB + vslice * 1024;

    float num[4] = {0.f, 0.f, 0.f, 0.f};
    float den[4] = {0.f, 0.f, 0.f, 0.f};
    const f32x4 z = {0.f, 0.f, 0.f, 0.f};

    for (int it = 0; it < 32; ++it) {
        int vb = it * 32;
        // A-frags direct from global (L2): A[m=v][k], lane: m=l15(+16), k=kf*32+quad*8+j
        const short* e0 = ep + (size_t)(vb + l15) * HS + quad * 8;
        const short* e1 = ep + (size_t)(vb + 16 + l15) * HS + quad * 8;
        bf16x8 a00 = *(const bf16x8*)(e0);
        bf16x8 a01 = *(const bf16x8*)(e0 + 32);
        bf16x8 a10 = *(const bf16x8*)(e1);
        bf16x8 a11 = *(const bf16x8*)(e1 + 32);
        f32x4 gv0 = *(const f32x4*)(gp + vb + quad * 4);
        f32x4 gv1 = *(const f32x4*)(gp + vb + 16 + quad * 4);
        #pragma unroll
        for (int qt = 0; qt < 4; ++qt) {
            f32x4 acc0 = __builtin_amdgcn_mfma_f32_16x16x32_bf16(a00, qf[qt][0], z, 0, 0, 0);
            acc0       = __builtin_amdgcn_mfma_f32_16x16x32_bf16(a01, qf[qt][1], acc0, 0, 0, 0);
            f32x4 acc1 = __builtin_amdgcn_mfma_f32_16x16x32_bf16(a10, qf[qt][0], z, 0, 0, 0);
            acc1       = __builtin_amdgcn_mfma_f32_16x16x32_bf16(a11, qf[qt][1], acc1, 0, 0, 0);
            // D layout: col=l15=q, row=quad*4+r = v-within-16-tile
            #pragma unroll
            for (int r = 0; r < 4; ++r) {
                float p0 = fexp2(acc0[r]);
                float p1 = fexp2(acc1[r]);
                den[qt] += p0 + p1;
                num[qt] += p0 * gv0[r] + p1 * gv1[r];
            }
        }
    }

    // reduce across quads (same l15 = same q)
    #pragma unroll
    for (int qt = 0; qt < 4; ++qt) {
        num[qt] += __shfl_xor(num[qt], 16); num[qt] += __shfl_xor(num[qt], 32);
        den[qt] += __shfl_xor(den[qt], 16); den[qt] += __shfl_xor(den[qt], 32);
    }
    // quad i commits q-tile i: one num + one den atomic per lane
    int qg = qbase + quad * 16 + l15;
    float nv = num[quad];   // small cndmask chains
    float dv = den[quad];
    float* pp = part + (size_t)(head * QPH + qg) * 2;
    atomicAdd(pp,     nv);
    atomicAdd(pp + 1, dv);
}

// ---------------- Kernel 3: out[q] = dec_b + sum_n num/den ---------------------------
__global__ void fin(const float* __restrict__ part, const float* __restrict__ dec_b,
                    float* __restrict__ out) {
    int q = blockIdx.x * 256 + threadIdx.x;   // 0..2047
    float s = dec_b[0];
    #pragma unroll
    for (int n = 0; n < NH; ++n) {
        float nv = part[(size_t)(n * QPH + q) * 2];
        float dv = part[(size_t)(n * QPH + q) * 2 + 1];
        s += nv / dv;
    }
    out[q] = s;
}

extern "C" void kernel_launch(void* const* d_in, const int* in_sizes, int n_in,
                              void* d_out, int out_size, void* d_ws, size_t ws_size,
                              hipStream_t stream) {
    const float* x     = (const float*)d_in[0];
    const float* emb   = (const float*)d_in[1];
    const float* enc_w = (const float*)d_in[2];
    const float* enc_b = (const float*)d_in[3];
    const float* ln_w  = (const float*)d_in[4];
    const float* ln_b  = (const float*)d_in[5];
    const float* dec_w = (const float*)d_in[6];
    const float* dec_b = (const float*)d_in[7];
    float* out = (float*)d_out;

    char* ws = (char*)d_ws;
    unsigned short* qbf  = (unsigned short*)(ws);                        // 2 MB
    unsigned short* ebf  = (unsigned short*)(ws + 2097152);              // 16 MB
    float*          g    = (float*)(ws + 2097152 + 16777216);            // 512 KB
    float*          part = (float*)(ws + 2097152 + 16777216 + 524288);   // 128 KB
    size_t part_bytes = (size_t)NH * QPH * 2 * sizeof(float);

    hipMemsetAsync(part, 0, part_bytes, stream);   // ws is re-poisoned before every launch
    hipLaunchKernelGGL(prep, dim3(12288), dim3(256), 0, stream,
                       x, emb, enc_w, enc_b, ln_w, ln_b, dec_w, qbf, ebf, g);
    hipLaunchKernelGGL(attn, dim3(1024), dim3(256), 0, stream, qbf, ebf, g, part);
    hipLaunchKernelGGL(fin,  dim3(8),    dim3(256), 0, stream, part, dec_b, out);
}